// Round 1
// baseline (523.912 us; speedup 1.0000x reference)
//
#include <hip/hip_runtime.h>

#define BATCH 4
#define SEQ   4096
#define HID   4096
#define OUTF  4096
#define NA    8
#define RANK  64

typedef __attribute__((ext_vector_type(8))) short  short8;
typedef __attribute__((ext_vector_type(4))) float  f32x4;

// round-half-up fp32 -> bf16 (inputs are finite Gaussians; no NaN handling needed)
__device__ __forceinline__ unsigned short cvt_bf16(float f) {
  return (unsigned short)((__float_as_uint(f) + 0x8000u) >> 16);
}
__device__ __forceinline__ unsigned int pack_bf16_2(float lo, float hi) {
  unsigned int a = __float_as_uint(lo);
  unsigned int b = __float_as_uint(hi);
  return ((a + 0x8000u) >> 16) | ((b + 0x8000u) & 0xFFFF0000u);
}

// ---------------------------------------------------------------------------
// Kernel 0: convert + transpose the small matrices so MFMA fragments are
// K-contiguous 16B loads.
//   Bct[a][r][h] = bf16(B[h][a][r])   (8 x 64 x 4096)
//   Act[a][o][r] = bf16(A[a][r][o])   (8 x 4096 x 64)
// blocks 0..511  -> B (a = bid>>6, h-tile = bid&63)
// blocks 512..1023 -> A (a = ..., o-tile = ...)
// ---------------------------------------------------------------------------
__global__ __launch_bounds__(256) void prep_kernel(
    const float* __restrict__ A, const float* __restrict__ Bm,
    unsigned short* __restrict__ Bct, unsigned short* __restrict__ Act) {
  __shared__ unsigned short lds[64 * 72];
  int bid = blockIdx.x;
  int t   = threadIdx.x;
  int lo  = t & 63;   // fast (coalesced) dim
  int hi4 = t >> 6;   // 0..3
  if (bid < 512) {
    int a  = bid >> 6;
    int h0 = (bid & 63) << 6;
    #pragma unroll
    for (int p = 0; p < 16; ++p) {          // read B[h][a][r], r = lo
      int hl = (p << 2) + hi4;
      float v = Bm[((size_t)(h0 + hl) * NA + a) * RANK + lo];
      lds[lo * 72 + hl] = cvt_bf16(v);      // lds[r][h]
    }
    __syncthreads();
    #pragma unroll
    for (int p = 0; p < 16; ++p) {          // write Bct[a][r][h], h = lo
      int rl = (p << 2) + hi4;
      Bct[((size_t)a * RANK + rl) * HID + h0 + lo] = lds[rl * 72 + lo];
    }
  } else {
    int b2 = bid - 512;
    int a  = b2 >> 6;
    int o0 = (b2 & 63) << 6;
    #pragma unroll
    for (int p = 0; p < 16; ++p) {          // read A[a][r][o], o = lo
      int rl = (p << 2) + hi4;
      float v = A[((size_t)a * RANK + rl) * OUTF + o0 + lo];
      lds[lo * 72 + rl] = cvt_bf16(v);      // lds[o][r]
    }
    __syncthreads();
    #pragma unroll
    for (int p = 0; p < 16; ++p) {          // write Act[a][o][r], r = lo
      int ol = (p << 2) + hi4;
      Act[((size_t)a * OUTF + o0 + ol) * RANK + lo] = lds[ol * 72 + lo];
    }
  }
}

// ---------------------------------------------------------------------------
// Kernel 1 (sdd): Bx[b][s][r] = sum_h x[b][s][h] * B[h][a_b][r]   (bf16 out)
// Grid: 1024 blocks = 4 batches x 256 s-tiles of 16 rows. Block = 4 waves.
// All 4 waves share the same 16x64 output tile; K (=4096) split 4 ways
// (1024 per wave) -> 16 waves/CU for latency hiding, no per-iter barriers.
// A-operand: x loaded fp32 direct from HBM, converted in-register.
// B-operand: Bct (L2-resident) 16B loads.
// Final cross-wave reduction through LDS, store bf16.
// ---------------------------------------------------------------------------
__global__ __launch_bounds__(256) void sdd_kernel(
    const float* __restrict__ x, const int* __restrict__ ids,
    const unsigned short* __restrict__ Bct, unsigned short* __restrict__ Bx) {
  __shared__ float red[4 * 16 * 65];
  int bid   = blockIdx.x;
  int batch = bid >> 8;
  int s0    = (bid & 255) << 4;
  int t     = threadIdx.x;
  int w     = t >> 6;
  int lane  = t & 63;
  int m     = lane & 15;   // M index of A-frag / also N index of B-frag
  int q     = lane >> 4;   // quad: k offset = q*8
  int a     = ids[batch];

  const float* xrow = x + (size_t)(batch * SEQ + s0 + m) * HID;
  const unsigned short* bbase = Bct + (size_t)a * RANK * HID;

  f32x4 acc[4];
  #pragma unroll
  for (int nt = 0; nt < 4; ++nt) acc[nt] = (f32x4){0.f, 0.f, 0.f, 0.f};

  int kw = w << 10;  // this wave's K range: [w*1024, w*1024+1024)
  for (int it = 0; it < 32; ++it) {
    int k = kw + (it << 5) + (q << 3);
    float4 f0 = *(const float4*)(xrow + k);
    float4 f1 = *(const float4*)(xrow + k + 4);
    union { short8 v; unsigned int u[4]; } af;
    af.u[0] = pack_bf16_2(f0.x, f0.y);
    af.u[1] = pack_bf16_2(f0.z, f0.w);
    af.u[2] = pack_bf16_2(f1.x, f1.y);
    af.u[3] = pack_bf16_2(f1.z, f1.w);
    #pragma unroll
    for (int nt = 0; nt < 4; ++nt) {
      // B-frag: lane holds B[k = q*8+j][n = nt*16+m]; Bct is [r][h] so this
      // is 8 contiguous bf16 at row (nt*16+m), col k.
      short8 bf = *(const short8*)(bbase + (size_t)(nt * 16 + m) * HID + k);
      acc[nt] = __builtin_amdgcn_mfma_f32_16x16x32_bf16(af.v, bf, acc[nt], 0, 0, 0);
    }
  }

  // C/D layout: col = lane&15 (-> r), row = q*4+reg (-> s)
  #pragma unroll
  for (int nt = 0; nt < 4; ++nt)
    #pragma unroll
    for (int r = 0; r < 4; ++r)
      red[(w * 16 + q * 4 + r) * 65 + nt * 16 + m] = acc[nt][r];
  __syncthreads();

  int row = t >> 4;          // 0..15
  int rb  = (t & 15) << 2;   // 0,4,...,60
  float v0 = red[(0 * 16 + row) * 65 + rb + 0] + red[(1 * 16 + row) * 65 + rb + 0]
           + red[(2 * 16 + row) * 65 + rb + 0] + red[(3 * 16 + row) * 65 + rb + 0];
  float v1 = red[(0 * 16 + row) * 65 + rb + 1] + red[(1 * 16 + row) * 65 + rb + 1]
           + red[(2 * 16 + row) * 65 + rb + 1] + red[(3 * 16 + row) * 65 + rb + 1];
  float v2 = red[(0 * 16 + row) * 65 + rb + 2] + red[(1 * 16 + row) * 65 + rb + 2]
           + red[(2 * 16 + row) * 65 + rb + 2] + red[(3 * 16 + row) * 65 + rb + 2];
  float v3 = red[(0 * 16 + row) * 65 + rb + 3] + red[(1 * 16 + row) * 65 + rb + 3]
           + red[(2 * 16 + row) * 65 + rb + 3] + red[(3 * 16 + row) * 65 + rb + 3];
  uint2 pk;
  pk.x = pack_bf16_2(v0, v1);
  pk.y = pack_bf16_2(v2, v3);
  *(uint2*)(Bx + (size_t)(batch * SEQ + s0 + row) * RANK + rb) = pk;
}

// ---------------------------------------------------------------------------
// Kernel 2 (dsd): out[b][s][o] = (sum_r Bx[b][s][r] * A[a][r][o]) / 64
// Grid: 16384 blocks = 4 x 64 s-tiles x 64 o-tiles of 64x64. Block = 4 waves,
// wave w owns a 16(s) x 64(o) band. K = 64 -> 2 ksteps, no LDS, no barriers.
// Bx and Act are L2-resident; the kernel is HBM-write-bound.
// ---------------------------------------------------------------------------
__global__ __launch_bounds__(256) void dsd_kernel(
    const unsigned short* __restrict__ Bx, const int* __restrict__ ids,
    const unsigned short* __restrict__ Act, float* __restrict__ out) {
  int bid   = blockIdx.x;
  int batch = bid >> 12;
  int rem   = bid & 4095;
  int sT    = rem >> 6;
  int oT    = rem & 63;
  int t     = threadIdx.x;
  int w     = t >> 6;
  int lane  = t & 63;
  int m     = lane & 15;
  int q     = lane >> 4;
  int a     = ids[batch];
  int s0    = (sT << 6) + (w << 4);
  int o0    = oT << 6;

  const unsigned short* bxrow = Bx + (size_t)(batch * SEQ + s0 + m) * RANK;
  const unsigned short* abase = Act + ((size_t)a * OUTF + o0) * RANK;

  short8 a0 = *(const short8*)(bxrow + (q << 3));        // k = 0..31
  short8 a1 = *(const short8*)(bxrow + 32 + (q << 3));   // k = 32..63

  f32x4 acc[4];
  #pragma unroll
  for (int nt = 0; nt < 4; ++nt) acc[nt] = (f32x4){0.f, 0.f, 0.f, 0.f};

  #pragma unroll
  for (int nt = 0; nt < 4; ++nt) {
    const unsigned short* arow = abase + (size_t)(nt * 16 + m) * RANK;
    short8 b0 = *(const short8*)(arow + (q << 3));
    short8 b1 = *(const short8*)(arow + 32 + (q << 3));
    acc[nt] = __builtin_amdgcn_mfma_f32_16x16x32_bf16(a0, b0, acc[nt], 0, 0, 0);
    acc[nt] = __builtin_amdgcn_mfma_f32_16x16x32_bf16(a1, b1, acc[nt], 0, 0, 0);
  }

  const float sc = 1.0f / 64.0f;
  float* orow = out + (size_t)(batch * SEQ + s0) * OUTF + o0;
  #pragma unroll
  for (int nt = 0; nt < 4; ++nt)
    #pragma unroll
    for (int r = 0; r < 4; ++r)
      orow[(size_t)(q * 4 + r) * OUTF + nt * 16 + m] = acc[nt][r] * sc;
}

// ---------------------------------------------------------------------------
extern "C" void kernel_launch(void* const* d_in, const int* in_sizes, int n_in,
                              void* d_out, int out_size, void* d_ws, size_t ws_size,
                              hipStream_t stream) {
  const float* x   = (const float*)d_in[0];
  const int*   ids = (const int*)d_in[1];
  const float* A   = (const float*)d_in[2];
  const float* Bm  = (const float*)d_in[3];
  float*       out = (float*)d_out;

  // workspace layout (10 MB total):
  unsigned short* Bct = (unsigned short*)d_ws;                 // 8*64*4096*2 = 4 MB
  unsigned short* Act = Bct + (size_t)NA * RANK * HID;         // 8*4096*64*2 = 4 MB
  unsigned short* Bx  = Act + (size_t)NA * OUTF * RANK;        // 4*4096*64*2 = 2 MB

  prep_kernel<<<1024, 256, 0, stream>>>(A, Bm, Bct, Act);
  sdd_kernel <<<1024, 256, 0, stream>>>(x, ids, Bct, Bx);
  dsd_kernel <<<16384, 256, 0, stream>>>(Bx, ids, Act, out);
}